// Round 17
// baseline (413.137 us; speedup 1.0000x reference)
//
#include <hip/hip_runtime.h>
#include <cstddef>

#define BSZ   8192
#define DIM   1024
#define NCON  64
#define NBANK 100000
#define NCLS  1000
#define TOPK  50
#define NCHUNK 32
#define CHUNK  3125    // 32 * 3125 = 100000
#define CHUNKP 3328    // 13 * 256 (padded with +inf)
#define NDIST 1563     // 1563 * 64 = 100032 >= 100000

#define Y_OFF 8192000
#define S_OFF 16384000

typedef __attribute__((ext_vector_type(8))) short bf16x8;
typedef __attribute__((ext_vector_type(4))) float f32x4;

__device__ __forceinline__ short f2bf(float x) {
    unsigned u = __builtin_bit_cast(unsigned, x);
    unsigned r = (u + 0x7fffu + ((u >> 16) & 1u)) >> 16;
    return (short)r;
}

__device__ __forceinline__ bf16x8 pack8(f32x4 a, f32x4 b) {
    bf16x8 p;
    p[0] = f2bf(a[0]); p[1] = f2bf(a[1]); p[2] = f2bf(a[2]); p[3] = f2bf(a[3]);
    p[4] = f2bf(b[0]); p[5] = f2bf(b[1]); p[6] = f2bf(b[2]); p[7] = f2bf(b[3]);
    return p;
}

// lds base must be WAVE-UNIFORM; hardware writes base + lane*16.
__device__ __forceinline__ void gload16(const void* g, void* l) {
    __builtin_amdgcn_global_load_lds(
        (__attribute__((address_space(1))) void*)g,
        (__attribute__((address_space(3))) void*)l,
        16, 0, 0);
}

// ================= L1: prep =================
// 0..255: Wh^T -> WhT [1024][1024] bf16 (cols>=1000 zero) ; 256..271: cpt -> cptT
__global__ void __launch_bounds__(256) prep_kernel(const float* __restrict__ cpt,
                                                   const float* __restrict__ Wh,
                                                   short* __restrict__ WhT,
                                                   short* __restrict__ cptT) {
    __shared__ short Ts[64][65];
    int b = blockIdx.x;
    int t = threadIdx.x;
    if (b < 256) {
        int k0 = (b & 15) * 64, n0 = (b >> 4) * 64;
        #pragma unroll
        for (int i = 0; i < 16; ++i) {
            int u = i * 256 + t;
            int kL = u >> 6, nL = u & 63;
            int n = n0 + nL;
            Ts[kL][nL] = (n < NCLS) ? f2bf(Wh[(size_t)(k0 + kL) * NCLS + n]) : (short)0;
        }
        __syncthreads();
        #pragma unroll
        for (int i = 0; i < 16; ++i) {
            int u = i * 256 + t;
            int nL = u >> 6, kL = u & 63;
            WhT[(size_t)(n0 + nL) * DIM + k0 + kL] = Ts[kL][nL];
        }
    } else {
        int q = b - 256;
        #pragma unroll
        for (int i = 0; i < 16; ++i) {
            int u = q * 4096 + i * 256 + t;
            int d = u >> 6, n = u & 63;
            cptT[n * DIM + d] = f2bf(cpt[u]);
        }
    }
}

// ================= L2: dist (standalone, R15-best: BK=64 staged dbuf) =================
__global__ void __launch_bounds__(256) dist_kernel(const float* __restrict__ bank,
                                                   const short* __restrict__ cptT,
                                                   float* __restrict__ key,
                                                   float* __restrict__ bank_sq) {
    __shared__ __align__(16) char smem[49152];  // 2x16KB bank f32 + 2x8KB cpt bf16
    int b = blockIdx.x;
    int t = threadIdx.x;
    int wid = t >> 6, l = t & 63, lr = l & 15, lg = l >> 4;
    int j0 = b * 64;
    int bj4[4], bs4[4];
    #pragma unroll
    for (int i = 0; i < 4; ++i) {
        int flat = i * 4096 + wid * 1024 + l * 16;   // byte in 16KB tile
        bj4[i] = flat >> 8;                           // row j (256 B/row)
        bs4[i] = ((flat >> 4) & 15) ^ (bj4[i] & 15);  // global segment for this slot
    }
    int cm2[2], cs2[2];
    #pragma unroll
    for (int i = 0; i < 2; ++i) {
        int flat = i * 4096 + wid * 1024 + l * 16;   // byte in 8KB tile
        cm2[i] = flat >> 7;                           // row m (128 B/row)
        cs2[i] = ((flat >> 4) & 7) ^ (cm2[i] & 7);
    }
    int jl = wid * 16 + lr;
    f32x4 acc[4] = {};
    float sq = 0.f;
    // prologue: stage step 0 into buffer 0
    #pragma unroll
    for (int i = 0; i < 4; ++i) {
        int jr = j0 + bj4[i]; if (jr >= NBANK) jr = NBANK - 1;
        gload16(bank + (size_t)jr * DIM + bs4[i] * 4, smem + i * 4096 + wid * 1024);
    }
    #pragma unroll
    for (int i = 0; i < 2; ++i)
        gload16(cptT + cm2[i] * DIM + cs2[i] * 8, smem + 32768 + i * 4096 + wid * 1024);
    int buf = 0;
    for (int kk = 0; kk < DIM; kk += 64) {
        __syncthreads();   // drains staging for `buf`
        int kn = kk + 64;
        int nb = buf ^ 1;
        if (kn < DIM) {
            #pragma unroll
            for (int i = 0; i < 4; ++i) {
                int jr = j0 + bj4[i]; if (jr >= NBANK) jr = NBANK - 1;
                gload16(bank + (size_t)jr * DIM + kn + bs4[i] * 4,
                        smem + nb * 16384 + i * 4096 + wid * 1024);
            }
            #pragma unroll
            for (int i = 0; i < 2; ++i)
                gload16(cptT + cm2[i] * DIM + kn + cs2[i] * 8,
                        smem + 32768 + nb * 8192 + i * 4096 + wid * 1024);
        }
        const float* bT = (const float*)(smem + buf * 16384);
        const short* cS = (const short*)(smem + 32768 + buf * 8192);
        #pragma unroll
        for (int ks = 0; ks < 2; ++ks) {
            bf16x8 af[4];
            #pragma unroll
            for (int mi = 0; mi < 4; ++mi) {
                int m = mi * 16 + lr;
                af[mi] = *(const bf16x8*)(cS + m * 64 + (((ks * 4 + lg) ^ (m & 7)) << 3));
            }
            int g0 = ks * 8 + lg * 2;
            f32x4 a = *(const f32x4*)(bT + jl * 64 + ((g0 ^ (jl & 15)) << 2));
            f32x4 c = *(const f32x4*)(bT + jl * 64 + (((g0 + 1) ^ (jl & 15)) << 2));
            sq += a[0]*a[0] + a[1]*a[1] + a[2]*a[2] + a[3]*a[3]
                + c[0]*c[0] + c[1]*c[1] + c[2]*c[2] + c[3]*c[3];
            bf16x8 pk = pack8(a, c);
            #pragma unroll
            for (int mi = 0; mi < 4; ++mi)
                acc[mi] = __builtin_amdgcn_mfma_f32_16x16x32_bf16(af[mi], pk, acc[mi], 0, 0, 0);
        }
        buf ^= 1;
    }
    sq += __shfl_xor(sq, 16);
    sq += __shfl_xor(sq, 32);
    int j = j0 + jl;
    if (j < NBANK) {
        if (lg == 0) bank_sq[j] = sq;
        #pragma unroll
        for (int mi = 0; mi < 4; ++mi)
            #pragma unroll
            for (int r = 0; r < 4; ++r) {
                int m = mi * 16 + lg * 4 + r;
                key[(size_t)m * NBANK + j] = sq - 2.f * acc[mi][r];
            }
    }
}

// ================= L3: aux (MbfT, G+invGbf, XC) + topA =================
// 0..7: MbfT ; 8: G+invGbf ; 9..72: XC (+ Xbf) ; 73..2120: topA
__global__ void __launch_bounds__(256) aux_topA_kernel(const float* __restrict__ X,
                                                       const short* __restrict__ cptT,
                                                       const short* __restrict__ WhT,
                                                       const float* __restrict__ key,
                                                       short* __restrict__ Xbf,
                                                       short* __restrict__ XCbf,
                                                       short* __restrict__ MbfT,
                                                       float* __restrict__ G,
                                                       short* __restrict__ invGbf,
                                                       float* __restrict__ cand_v,
                                                       int* __restrict__ cand_j) {
    __shared__ float vals[CHUNKP];
    __shared__ float wv[4];
    __shared__ int wj[4];
    int b = blockIdx.x;
    int t = threadIdx.x;
    int wid = t >> 6, l = t & 63, lr = l & 15, lg = l >> 4;
    if (b < 8) {
        // ---- MbfT[c][m] = bf16( (C^T @ Wh)[m][c] ) ----
        int c0 = b * 128;
        f32x4 acc[4][2] = {};
        for (int kk = 0; kk < DIM; kk += 32) {
            bf16x8 af[4], bfr[2];
            #pragma unroll
            for (int mi = 0; mi < 4; ++mi)
                af[mi] = *(const bf16x8*)(cptT + (mi * 16 + lr) * DIM + kk + lg * 8);
            #pragma unroll
            for (int ni = 0; ni < 2; ++ni)
                bfr[ni] = *(const bf16x8*)(WhT + (size_t)(c0 + wid * 32 + ni * 16 + lr) * DIM + kk + lg * 8);
            #pragma unroll
            for (int mi = 0; mi < 4; ++mi)
                #pragma unroll
                for (int ni = 0; ni < 2; ++ni)
                    acc[mi][ni] = __builtin_amdgcn_mfma_f32_16x16x32_bf16(af[mi], bfr[ni], acc[mi][ni], 0, 0, 0);
        }
        #pragma unroll
        for (int mi = 0; mi < 4; ++mi)
            #pragma unroll
            for (int ni = 0; ni < 2; ++ni)
                #pragma unroll
                for (int r = 0; r < 4; ++r) {
                    int m = mi * 16 + lg * 4 + r;
                    int c = c0 + wid * 32 + ni * 16 + lr;
                    MbfT[(size_t)c * NCON + m] = f2bf(acc[mi][ni][r]);
                }
    } else if (b == 8) {
        // ---- G = C^T C via MFMA, then register Gauss-Jordan -> invGbf ----
        float* rowk = vals;
        float* fk = vals + 64;
        f32x4 acc[4] = {};
        for (int kk = 0; kk < DIM; kk += 32) {
            bf16x8 af[4], bfr;
            #pragma unroll
            for (int mi = 0; mi < 4; ++mi)
                af[mi] = *(const bf16x8*)(cptT + (mi * 16 + lr) * DIM + kk + lg * 8);
            bfr = *(const bf16x8*)(cptT + (wid * 16 + lr) * DIM + kk + lg * 8);
            #pragma unroll
            for (int mi = 0; mi < 4; ++mi)
                acc[mi] = __builtin_amdgcn_mfma_f32_16x16x32_bf16(af[mi], bfr, acc[mi], 0, 0, 0);
        }
        #pragma unroll
        for (int mi = 0; mi < 4; ++mi)
            #pragma unroll
            for (int r = 0; r < 4; ++r)
                G[(mi * 16 + lg * 4 + r) * 64 + wid * 16 + lr] = acc[mi][r];
        __syncthreads();   // drain vmcnt: G visible to own reads via L2
        float myA[16];
        #pragma unroll
        for (int s = 0; s < 16; ++s) myA[s] = G[(4 * s + wid) * 64 + l];
        #pragma unroll
        for (int k = 0; k < 64; ++k) {
            if (wid == (k & 3)) rowk[l] = myA[k >> 2];
            if (l == k) {
                #pragma unroll
                for (int s = 0; s < 16; ++s) fk[4 * s + wid] = myA[s];
            }
            __syncthreads();
            float ip = 1.f / rowk[k];
            float rv = rowk[l];
            #pragma unroll
            for (int s = 0; s < 16; ++s) {
                int i = 4 * s + wid;
                float fv = fk[i];
                float nv;
                if (i == k && l == k)      nv = ip;
                else if (i == k)           nv = rv * ip;
                else if (l == k)           nv = -fv * ip;
                else                       nv = myA[s] - fv * (rv * ip);
                myA[s] = nv;
            }
            __syncthreads();
        }
        #pragma unroll
        for (int s = 0; s < 16; ++s) invGbf[(4 * s + wid) * 64 + l] = f2bf(myA[s]);
    } else if (b < 73) {
        // ---- XC = X @ C (also writes Xbf bf16) ----
        int r0 = (b - 9) * 128;
        int r_[2];
        const float* xrow[2];
        #pragma unroll
        for (int ni = 0; ni < 2; ++ni) {
            r_[ni] = r0 + wid * 32 + ni * 16 + lr;
            xrow[ni] = X + (size_t)r_[ni] * DIM + lg * 8;
        }
        f32x4 acc[4][2] = {};
        for (int kk = 0; kk < DIM; kk += 32) {
            bf16x8 af[4];
            #pragma unroll
            for (int mi = 0; mi < 4; ++mi)
                af[mi] = *(const bf16x8*)(cptT + (mi * 16 + lr) * DIM + kk + lg * 8);
            #pragma unroll
            for (int ni = 0; ni < 2; ++ni) {
                f32x4 a = *(const f32x4*)(xrow[ni] + kk);
                f32x4 c = *(const f32x4*)(xrow[ni] + kk + 4);
                bf16x8 pk = pack8(a, c);
                *(bf16x8*)(Xbf + (size_t)r_[ni] * DIM + kk + lg * 8) = pk;
                #pragma unroll
                for (int mi = 0; mi < 4; ++mi)
                    acc[mi][ni] = __builtin_amdgcn_mfma_f32_16x16x32_bf16(af[mi], pk, acc[mi][ni], 0, 0, 0);
            }
        }
        #pragma unroll
        for (int mi = 0; mi < 4; ++mi)
            #pragma unroll
            for (int ni = 0; ni < 2; ++ni)
                #pragma unroll
                for (int r = 0; r < 4; ++r) {
                    int m = mi * 16 + lg * 4 + r;
                    XCbf[(size_t)r_[ni] * NCON + m] = f2bf(acc[mi][ni][r]);
                }
    } else {
        // ---- topA: per-(concept,chunk) top-50 ----
        int q = b - 73;
        int n = q >> 5;
        int c = q & 31;
        int base = c * CHUNK;
        const float* row = key + (size_t)n * NBANK + base;
        float lv = __builtin_inff();
        int lj = 0x7fffffff;
        #pragma unroll 13
        for (int i = 0; i < 13; ++i) {
            int j = t + i * 256;
            float v = (j < CHUNK) ? row[j] : __builtin_inff();
            vals[j] = v;
            if (v < lv) { lv = v; lj = j; }
        }
        __syncthreads();
        float* cv = cand_v + (size_t)q * TOPK;
        int* cj = cand_j + (size_t)q * TOPK;
        for (int it = 0; it < TOPK; ++it) {
            float bv = lv; int bj = lj;
            #pragma unroll
            for (int o = 32; o > 0; o >>= 1) {
                float ov = __shfl_down(bv, o);
                int oj = __shfl_down(bj, o);
                if (ov < bv || (ov == bv && oj < bj)) { bv = ov; bj = oj; }
            }
            if ((t & 63) == 0) { wv[t >> 6] = bv; wj[t >> 6] = bj; }
            __syncthreads();
            float gv = wv[0]; int gj = wj[0];
            #pragma unroll
            for (int w2 = 1; w2 < 4; ++w2)
                if (wv[w2] < gv || (wv[w2] == gv && wj[w2] < gj)) { gv = wv[w2]; gj = wj[w2]; }
            if (t == 0) { cv[it] = gv; cj[it] = base + gj; }
            if (t == (gj & 255)) {
                vals[gj] = __builtin_inff();
                lv = __builtin_inff(); lj = 0x7fffffff;
                #pragma unroll 13
                for (int i = 0; i < 13; ++i) {
                    int j = t + i * 256;
                    float v = vals[j];
                    if (v < lv) { lv = v; lj = j; }
                }
            }
            __syncthreads();
        }
    }
}

// ================= L4: orig GEMM + M2 + topB =================
// 0..511: orig ; 512..519: M2 ; 520..583: topB
__global__ void __launch_bounds__(256) pred_kernel(const short* __restrict__ Xbf,
                                                   const short* __restrict__ WhT,
                                                   const short* __restrict__ invGbf,
                                                   const short* __restrict__ MbfT,
                                                   const float* __restrict__ bh,
                                                   const float* __restrict__ cand_v,
                                                   const int* __restrict__ cand_j,
                                                   const float* __restrict__ bank_sq,
                                                   float* __restrict__ orig,
                                                   short* __restrict__ M2T,
                                                   float* __restrict__ dots) {
    __shared__ __align__(16) char smem[32768];
    int b = blockIdx.x;
    int t = threadIdx.x;
    int wid = t >> 6, l = t & 63, lr = l & 15, lg = l >> 4;
    if (b < 512) {
        // ---- orig = Xbf @ WhT^T + bh  [8192 x 1000], K=1024 ----
        short* As = (short*)smem;            // [128][64] bf16
        short* Bs = (short*)(smem + 16384);
        int c0 = (b & 7) * 128;
        int r0 = (b >> 3) * 128;
        int wr = wid >> 1, wc = wid & 1;
        int srow_off = l >> 3;
        int scol = ((l & 7) ^ (l >> 3)) * 8;
        f32x4 acc[4][4] = {};
        for (int kk = 0; kk < DIM; kk += 64) {
            if (kk) __syncthreads();
            #pragma unroll
            for (int i = 0; i < 4; ++i) {
                int si = wid * 4 + i;
                int row = si * 8 + srow_off;
                gload16(Xbf + (size_t)(r0 + row) * DIM + kk + scol, As + si * 512);
                gload16(WhT + (size_t)(c0 + row) * DIM + kk + scol, Bs + si * 512);
            }
            __syncthreads();
            #pragma unroll
            for (int ks = 0; ks < 2; ++ks) {
                bf16x8 af[4], bfr[4];
                #pragma unroll
                for (int mi = 0; mi < 4; ++mi) {
                    int rr = wr * 64 + mi * 16 + lr;
                    int slot = (ks * 4 + lg) ^ (rr & 7);
                    af[mi] = *(const bf16x8*)(As + rr * 64 + slot * 8);
                }
                #pragma unroll
                for (int ni = 0; ni < 4; ++ni) {
                    int cc = wc * 64 + ni * 16 + lr;
                    int slot = (ks * 4 + lg) ^ (cc & 7);
                    bfr[ni] = *(const bf16x8*)(Bs + cc * 64 + slot * 8);
                }
                #pragma unroll
                for (int mi = 0; mi < 4; ++mi)
                    #pragma unroll
                    for (int ni = 0; ni < 4; ++ni)
                        acc[mi][ni] = __builtin_amdgcn_mfma_f32_16x16x32_bf16(af[mi], bfr[ni], acc[mi][ni], 0, 0, 0);
            }
        }
        #pragma unroll
        for (int mi = 0; mi < 4; ++mi)
            #pragma unroll
            for (int ni = 0; ni < 4; ++ni) {
                int col = c0 + wc * 64 + ni * 16 + lr;
                if (col < NCLS) {
                    float bias = bh[col];
                    #pragma unroll
                    for (int r = 0; r < 4; ++r) {
                        int row = r0 + wr * 64 + mi * 16 + lg * 4 + r;
                        orig[(size_t)row * NCLS + col] = acc[mi][ni][r] + bias;
                    }
                }
            }
    } else if (b < 520) {
        // ---- M2T[c][n] = bf16( sum_j invG[n][j] * M[j][c] ), K=64 MFMA, no LDS ----
        int c0 = (b - 512) * 128;
        f32x4 acc[4][2] = {};
        #pragma unroll
        for (int ks = 0; ks < 2; ++ks) {
            bf16x8 af[4], bfr[2];
            #pragma unroll
            for (int mi = 0; mi < 4; ++mi)
                af[mi] = *(const bf16x8*)(invGbf + (mi * 16 + lr) * NCON + ks * 32 + lg * 8);
            #pragma unroll
            for (int ni = 0; ni < 2; ++ni)
                bfr[ni] = *(const bf16x8*)(MbfT + (size_t)(c0 + wid * 32 + ni * 16 + lr) * NCON + ks * 32 + lg * 8);
            #pragma unroll
            for (int mi = 0; mi < 4; ++mi)
                #pragma unroll
                for (int ni = 0; ni < 2; ++ni)
                    acc[mi][ni] = __builtin_amdgcn_mfma_f32_16x16x32_bf16(af[mi], bfr[ni], acc[mi][ni], 0, 0, 0);
        }
        #pragma unroll
        for (int mi = 0; mi < 4; ++mi)
            #pragma unroll
            for (int ni = 0; ni < 2; ++ni)
                #pragma unroll
                for (int r = 0; r < 4; ++r) {
                    int n = mi * 16 + lg * 4 + r;
                    int c = c0 + wid * 32 + ni * 16 + lr;
                    M2T[(size_t)c * NCON + n] = f2bf(acc[mi][ni][r]);
                }
    } else {
        // ---- topB: merge 32*50 candidates per concept ----
        int n = b - 520;
        const int NC2 = NCHUNK * TOPK;  // 1600
        float* vals = (float*)smem;
        int* gidx = (int*)(smem + 6400);
        float* wv = (float*)(smem + 12800);
        int* wj = (int*)(smem + 12816);
        int* wl = (int*)(smem + 12832);
        for (int j = t; j < NC2; j += 256) {
            vals[j] = cand_v[(size_t)n * NC2 + j];
            gidx[j] = cand_j[(size_t)n * NC2 + j];
        }
        __syncthreads();
        float sum = 0.f;
        for (int it = 0; it < TOPK; ++it) {
            float bv = __builtin_inff();
            int bj = 0x7fffffff;
            int bl = -1;
            #pragma unroll 7
            for (int j = t; j < NC2; j += 256) {
                float v = vals[j];
                int gj = gidx[j];
                if (v < bv || (v == bv && gj < bj)) { bv = v; bj = gj; bl = j; }
            }
            #pragma unroll
            for (int o = 32; o > 0; o >>= 1) {
                float ov = __shfl_down(bv, o);
                int oj = __shfl_down(bj, o);
                int ol = __shfl_down(bl, o);
                if (ov < bv || (ov == bv && oj < bj)) { bv = ov; bj = oj; bl = ol; }
            }
            if ((t & 63) == 0) { wv[t >> 6] = bv; wj[t >> 6] = bj; wl[t >> 6] = bl; }
            __syncthreads();
            if (t == 0) {
                #pragma unroll
                for (int w2 = 1; w2 < 4; ++w2)
                    if (wv[w2] < bv || (wv[w2] == bv && wj[w2] < bj)) { bv = wv[w2]; bj = wj[w2]; bl = wl[w2]; }
                sum += 0.5f * (bank_sq[bj] - bv);
                vals[bl] = __builtin_inff();
            }
            __syncthreads();
        }
        if (t == 0) dots[n] = sum / (float)TOPK;
    }
}

// ================= L5: ypred + fin =================
// 0..511: ypred ; 512: fin
__global__ void __launch_bounds__(256) ypred_fin_kernel(const short* __restrict__ XCbf,
                                                        const short* __restrict__ M2T,
                                                        const float* __restrict__ bh,
                                                        const float* __restrict__ G,
                                                        const float* __restrict__ dots,
                                                        float* __restrict__ ypred,
                                                        float* __restrict__ out3) {
    __shared__ float r1[256], r2[256], r3[256];
    int b = blockIdx.x;
    int t = threadIdx.x;
    if (b < 512) {
        int wid = t >> 6, l = t & 63, lr = l & 15, lg = l >> 4;
        int c0 = (b & 7) * 128;
        int r0 = (b >> 3) * 128;
        int wr = wid >> 1, wc = wid & 1;
        f32x4 acc[4][4] = {};
        #pragma unroll
        for (int ks = 0; ks < 2; ++ks) {
            bf16x8 af[4], bfr[4];
            #pragma unroll
            for (int mi = 0; mi < 4; ++mi)
                af[mi] = *(const bf16x8*)(XCbf + (size_t)(r0 + wr * 64 + mi * 16 + lr) * NCON + ks * 32 + lg * 8);
            #pragma unroll
            for (int ni = 0; ni < 4; ++ni)
                bfr[ni] = *(const bf16x8*)(M2T + (size_t)(c0 + wc * 64 + ni * 16 + lr) * NCON + ks * 32 + lg * 8);
            #pragma unroll
            for (int mi = 0; mi < 4; ++mi)
                #pragma unroll
                for (int ni = 0; ni < 4; ++ni)
                    acc[mi][ni] = __builtin_amdgcn_mfma_f32_16x16x32_bf16(af[mi], bfr[ni], acc[mi][ni], 0, 0, 0);
        }
        #pragma unroll
        for (int mi = 0; mi < 4; ++mi)
            #pragma unroll
            for (int ni = 0; ni < 4; ++ni) {
                int col = c0 + wc * 64 + ni * 16 + lr;
                if (col < NCLS) {
                    float bias = bh[col];
                    #pragma unroll
                    for (int r = 0; r < 4; ++r) {
                        int row = r0 + wr * 64 + mi * 16 + lg * 4 + r;
                        ypred[(size_t)row * NCLS + col] = acc[mi][ni][r] + bias;
                    }
                }
            }
    } else {
        float sd = 0.f, so = 0.f;
        for (int u = t; u < 4096; u += 256) {
            float g = G[u];
            if ((u >> 6) == (u & 63)) sd += g; else so += g;
        }
        float s1 = (t < NCON) ? dots[t] : 0.f;
        r1[t] = sd; r2[t] = so; r3[t] = s1;
        __syncthreads();
        for (int o = 128; o > 0; o >>= 1) {
            if (t < o) { r1[t] += r1[t + o]; r2[t] += r2[t + o]; r3[t] += r3[t + o]; }
            __syncthreads();
        }
        if (t == 0) {
            out3[0] = r3[0] / 64.f;
            out3[1] = r2[0] / 4096.f;
            out3[2] = r1[0] / 4096.f;
        }
    }
}

extern "C" void kernel_launch(void* const* d_in, const int* in_sizes, int n_in,
                              void* d_out, int out_size, void* d_ws, size_t ws_size,
                              hipStream_t stream) {
    const float* X    = (const float*)d_in[0];
    const float* cpt  = (const float*)d_in[1];
    const float* bank = (const float*)d_in[2];
    const float* Wh   = (const float*)d_in[3];
    const float* bh   = (const float*)d_in[4];
    float* out = (float*)d_out;

    float* orig  = out;
    float* ypred = out + Y_OFF;
    float* out3  = out + S_OFF;

    char* w = (char*)d_ws;
    short* Xbf    = (short*)(w);               // 16,777,216 B
    short* WhT    = (short*)(w + 16777216);    //  2,097,152 B  [1024][1024] bf16
    short* cptT   = (short*)(w + 18874368);    //    131,072 B
    short* XCbf   = (short*)(w + 19005440);    //  1,048,576 B  [8192][64] bf16
    short* M2T    = (short*)(w + 20054016);    //    131,072 B  [1024][64] bf16
    float* key    = (float*)(w + 20185088);    // 25,600,000 B
    float* bank_sq= (float*)(w + 45785088);    //    400,384 B
    float* G      = (float*)(w + 46185472);    //     16,384 B
    short* invGbf = (short*)(w + 46201856);    //      8,192 B  [64][64] bf16
    short* MbfT   = (short*)(w + 46210048);    //    131,072 B  [1024][64] bf16
    float* cand_v = (float*)(w + 46341120);    //    409,600 B
    int*   cand_j = (int*)  (w + 46750720);    //    409,600 B
    float* dots   = (float*)(w + 47160320);    //        256 B

    prep_kernel<<<272, 256, 0, stream>>>(cpt, Wh, WhT, cptT);
    dist_kernel<<<NDIST, 256, 0, stream>>>(bank, cptT, key, bank_sq);
    aux_topA_kernel<<<73 + 2048, 256, 0, stream>>>(X, cptT, WhT, key, Xbf, XCbf, MbfT, G, invGbf, cand_v, cand_j);
    pred_kernel<<<584, 256, 0, stream>>>(Xbf, WhT, invGbf, MbfT, bh, cand_v, cand_j, bank_sq, orig, M2T, dots);
    ypred_fin_kernel<<<513, 256, 0, stream>>>(XCbf, M2T, bh, G, dots, ypred, out3);
}

// Round 18
// 378.124 us; speedup vs baseline: 1.0926x; 1.0926x over previous
//
#include <hip/hip_runtime.h>
#include <cstddef>

#define BSZ   8192
#define DIM   1024
#define NCON  64
#define NBANK 100000
#define NCLS  1000
#define TOPK  50
#define NCHUNK 32
#define CHUNK  3125    // 32 * 3125 = 100000
#define CHUNKP 3328    // 13 * 256 (padded with +inf)
#define NDIST 1563     // 1563 * 64 = 100032 >= 100000

#define Y_OFF 8192000
#define S_OFF 16384000

typedef __attribute__((ext_vector_type(8))) short bf16x8;
typedef __attribute__((ext_vector_type(4))) float f32x4;

__device__ __forceinline__ short f2bf(float x) {
    unsigned u = __builtin_bit_cast(unsigned, x);
    unsigned r = (u + 0x7fffu + ((u >> 16) & 1u)) >> 16;
    return (short)r;
}

__device__ __forceinline__ bf16x8 pack8(f32x4 a, f32x4 b) {
    bf16x8 p;
    p[0] = f2bf(a[0]); p[1] = f2bf(a[1]); p[2] = f2bf(a[2]); p[3] = f2bf(a[3]);
    p[4] = f2bf(b[0]); p[5] = f2bf(b[1]); p[6] = f2bf(b[2]); p[7] = f2bf(b[3]);
    return p;
}

// lds base must be WAVE-UNIFORM; hardware writes base + lane*16.
__device__ __forceinline__ void gload16(const void* g, void* l) {
    __builtin_amdgcn_global_load_lds(
        (__attribute__((address_space(1))) void*)g,
        (__attribute__((address_space(3))) void*)l,
        16, 0, 0);
}

// ================= L1: prep =================
// 0..255: Wh^T -> WhT [1024][1024] bf16 (cols>=1000 zero) ; 256..271: cpt -> cptT
__global__ void __launch_bounds__(256) prep_kernel(const float* __restrict__ cpt,
                                                   const float* __restrict__ Wh,
                                                   short* __restrict__ WhT,
                                                   short* __restrict__ cptT) {
    __shared__ short Ts[64][65];
    int b = blockIdx.x;
    int t = threadIdx.x;
    if (b < 256) {
        int k0 = (b & 15) * 64, n0 = (b >> 4) * 64;
        #pragma unroll
        for (int i = 0; i < 16; ++i) {
            int u = i * 256 + t;
            int kL = u >> 6, nL = u & 63;
            int n = n0 + nL;
            Ts[kL][nL] = (n < NCLS) ? f2bf(Wh[(size_t)(k0 + kL) * NCLS + n]) : (short)0;
        }
        __syncthreads();
        #pragma unroll
        for (int i = 0; i < 16; ++i) {
            int u = i * 256 + t;
            int nL = u >> 6, kL = u & 63;
            WhT[(size_t)(n0 + nL) * DIM + k0 + kL] = Ts[kL][nL];
        }
    } else {
        int q = b - 256;
        #pragma unroll
        for (int i = 0; i < 16; ++i) {
            int u = q * 4096 + i * 256 + t;
            int d = u >> 6, n = u & 63;
            cptT[n * DIM + d] = f2bf(cpt[u]);
        }
    }
}

// ================= L2: mid =================
// 0..7: MbfT ; 8: G+invGbf ; 9..72: XC (+ Xbf) ; 73..1635: dist (BK=64 staged)
__global__ void __launch_bounds__(256) mid_kernel(const float* __restrict__ bank,
                                                  const float* __restrict__ X,
                                                  const short* __restrict__ cptT,
                                                  const short* __restrict__ WhT,
                                                  short* __restrict__ Xbf,
                                                  short* __restrict__ XCbf,
                                                  float* __restrict__ key,
                                                  float* __restrict__ bank_sq,
                                                  short* __restrict__ MbfT,
                                                  float* __restrict__ G,
                                                  short* __restrict__ invGbf) {
    __shared__ __align__(16) char smem[49152];  // dist: 2x16KB bank + 2x8KB cpt ; GJ: 512B
    int b = blockIdx.x;
    int t = threadIdx.x;
    int wid = t >> 6, l = t & 63, lr = l & 15, lg = l >> 4;
    if (b < 8) {
        // ---- MbfT[c][m] = bf16( (C^T @ Wh)[m][c] ) ----
        int c0 = b * 128;
        f32x4 acc[4][2] = {};
        for (int kk = 0; kk < DIM; kk += 32) {
            bf16x8 af[4], bfr[2];
            #pragma unroll
            for (int mi = 0; mi < 4; ++mi)
                af[mi] = *(const bf16x8*)(cptT + (mi * 16 + lr) * DIM + kk + lg * 8);
            #pragma unroll
            for (int ni = 0; ni < 2; ++ni)
                bfr[ni] = *(const bf16x8*)(WhT + (size_t)(c0 + wid * 32 + ni * 16 + lr) * DIM + kk + lg * 8);
            #pragma unroll
            for (int mi = 0; mi < 4; ++mi)
                #pragma unroll
                for (int ni = 0; ni < 2; ++ni)
                    acc[mi][ni] = __builtin_amdgcn_mfma_f32_16x16x32_bf16(af[mi], bfr[ni], acc[mi][ni], 0, 0, 0);
        }
        #pragma unroll
        for (int mi = 0; mi < 4; ++mi)
            #pragma unroll
            for (int ni = 0; ni < 2; ++ni)
                #pragma unroll
                for (int r = 0; r < 4; ++r) {
                    int m = mi * 16 + lg * 4 + r;
                    int c = c0 + wid * 32 + ni * 16 + lr;
                    MbfT[(size_t)c * NCON + m] = f2bf(acc[mi][ni][r]);
                }
    } else if (b == 8) {
        // ---- G = C^T C via MFMA, then register Gauss-Jordan -> invGbf ----
        float* rowk = (float*)smem;
        float* fk = (float*)(smem + 256);
        f32x4 acc[4] = {};
        for (int kk = 0; kk < DIM; kk += 32) {
            bf16x8 af[4], bfr;
            #pragma unroll
            for (int mi = 0; mi < 4; ++mi)
                af[mi] = *(const bf16x8*)(cptT + (mi * 16 + lr) * DIM + kk + lg * 8);
            bfr = *(const bf16x8*)(cptT + (wid * 16 + lr) * DIM + kk + lg * 8);
            #pragma unroll
            for (int mi = 0; mi < 4; ++mi)
                acc[mi] = __builtin_amdgcn_mfma_f32_16x16x32_bf16(af[mi], bfr, acc[mi], 0, 0, 0);
        }
        #pragma unroll
        for (int mi = 0; mi < 4; ++mi)
            #pragma unroll
            for (int r = 0; r < 4; ++r)
                G[(mi * 16 + lg * 4 + r) * 64 + wid * 16 + lr] = acc[mi][r];
        __syncthreads();   // drain vmcnt: G visible to own reads via L2
        float myA[16];
        #pragma unroll
        for (int s = 0; s < 16; ++s) myA[s] = G[(4 * s + wid) * 64 + l];
        #pragma unroll
        for (int k = 0; k < 64; ++k) {
            if (wid == (k & 3)) rowk[l] = myA[k >> 2];
            if (l == k) {
                #pragma unroll
                for (int s = 0; s < 16; ++s) fk[4 * s + wid] = myA[s];
            }
            __syncthreads();
            float ip = 1.f / rowk[k];
            float rv = rowk[l];
            #pragma unroll
            for (int s = 0; s < 16; ++s) {
                int i = 4 * s + wid;
                float fv = fk[i];
                float nv;
                if (i == k && l == k)      nv = ip;
                else if (i == k)           nv = rv * ip;
                else if (l == k)           nv = -fv * ip;
                else                       nv = myA[s] - fv * (rv * ip);
                myA[s] = nv;
            }
            __syncthreads();
        }
        #pragma unroll
        for (int s = 0; s < 16; ++s) invGbf[(4 * s + wid) * 64 + l] = f2bf(myA[s]);
    } else if (b < 73) {
        // ---- XC = X @ C (also writes Xbf bf16) ----
        int r0 = (b - 9) * 128;
        int r_[2];
        const float* xrow[2];
        #pragma unroll
        for (int ni = 0; ni < 2; ++ni) {
            r_[ni] = r0 + wid * 32 + ni * 16 + lr;
            xrow[ni] = X + (size_t)r_[ni] * DIM + lg * 8;
        }
        f32x4 acc[4][2] = {};
        for (int kk = 0; kk < DIM; kk += 32) {
            bf16x8 af[4];
            #pragma unroll
            for (int mi = 0; mi < 4; ++mi)
                af[mi] = *(const bf16x8*)(cptT + (mi * 16 + lr) * DIM + kk + lg * 8);
            #pragma unroll
            for (int ni = 0; ni < 2; ++ni) {
                f32x4 a = *(const f32x4*)(xrow[ni] + kk);
                f32x4 c = *(const f32x4*)(xrow[ni] + kk + 4);
                bf16x8 pk = pack8(a, c);
                *(bf16x8*)(Xbf + (size_t)r_[ni] * DIM + kk + lg * 8) = pk;
                #pragma unroll
                for (int mi = 0; mi < 4; ++mi)
                    acc[mi][ni] = __builtin_amdgcn_mfma_f32_16x16x32_bf16(af[mi], pk, acc[mi][ni], 0, 0, 0);
            }
        }
        #pragma unroll
        for (int mi = 0; mi < 4; ++mi)
            #pragma unroll
            for (int ni = 0; ni < 2; ++ni)
                #pragma unroll
                for (int r = 0; r < 4; ++r) {
                    int m = mi * 16 + lg * 4 + r;
                    XCbf[(size_t)r_[ni] * NCON + m] = f2bf(acc[mi][ni][r]);
                }
    } else {
        // ---- dist: 64 j/block, BK=64, double-buffered global_load_lds staging ----
        int j0 = (b - 73) * 64;
        int bj4[4], bs4[4];
        #pragma unroll
        for (int i = 0; i < 4; ++i) {
            int flat = i * 4096 + wid * 1024 + l * 16;   // byte in 16KB tile
            bj4[i] = flat >> 8;                           // row j (256 B/row)
            bs4[i] = ((flat >> 4) & 15) ^ (bj4[i] & 15);  // global segment for this slot
        }
        int cm2[2], cs2[2];
        #pragma unroll
        for (int i = 0; i < 2; ++i) {
            int flat = i * 4096 + wid * 1024 + l * 16;   // byte in 8KB tile
            cm2[i] = flat >> 7;                           // row m (128 B/row)
            cs2[i] = ((flat >> 4) & 7) ^ (cm2[i] & 7);
        }
        int jl = wid * 16 + lr;
        f32x4 acc[4] = {};
        float sq = 0.f;
        // prologue: stage step 0 into buffer 0
        #pragma unroll
        for (int i = 0; i < 4; ++i) {
            int jr = j0 + bj4[i]; if (jr >= NBANK) jr = NBANK - 1;
            gload16(bank + (size_t)jr * DIM + bs4[i] * 4, smem + i * 4096 + wid * 1024);
        }
        #pragma unroll
        for (int i = 0; i < 2; ++i)
            gload16(cptT + cm2[i] * DIM + cs2[i] * 8, smem + 32768 + i * 4096 + wid * 1024);
        int buf = 0;
        for (int kk = 0; kk < DIM; kk += 64) {
            __syncthreads();   // drains staging for `buf`
            int kn = kk + 64;
            int nb = buf ^ 1;
            if (kn < DIM) {
                #pragma unroll
                for (int i = 0; i < 4; ++i) {
                    int jr = j0 + bj4[i]; if (jr >= NBANK) jr = NBANK - 1;
                    gload16(bank + (size_t)jr * DIM + kn + bs4[i] * 4,
                            smem + nb * 16384 + i * 4096 + wid * 1024);
                }
                #pragma unroll
                for (int i = 0; i < 2; ++i)
                    gload16(cptT + cm2[i] * DIM + kn + cs2[i] * 8,
                            smem + 32768 + nb * 8192 + i * 4096 + wid * 1024);
            }
            const float* bT = (const float*)(smem + buf * 16384);
            const short* cS = (const short*)(smem + 32768 + buf * 8192);
            #pragma unroll
            for (int ks = 0; ks < 2; ++ks) {
                bf16x8 af[4];
                #pragma unroll
                for (int mi = 0; mi < 4; ++mi) {
                    int m = mi * 16 + lr;
                    af[mi] = *(const bf16x8*)(cS + m * 64 + (((ks * 4 + lg) ^ (m & 7)) << 3));
                }
                int g0 = ks * 8 + lg * 2;
                f32x4 a = *(const f32x4*)(bT + jl * 64 + ((g0 ^ (jl & 15)) << 2));
                f32x4 c = *(const f32x4*)(bT + jl * 64 + (((g0 + 1) ^ (jl & 15)) << 2));
                sq += a[0]*a[0] + a[1]*a[1] + a[2]*a[2] + a[3]*a[3]
                    + c[0]*c[0] + c[1]*c[1] + c[2]*c[2] + c[3]*c[3];
                bf16x8 pk = pack8(a, c);
                #pragma unroll
                for (int mi = 0; mi < 4; ++mi)
                    acc[mi] = __builtin_amdgcn_mfma_f32_16x16x32_bf16(af[mi], pk, acc[mi], 0, 0, 0);
            }
            buf ^= 1;
        }
        sq += __shfl_xor(sq, 16);
        sq += __shfl_xor(sq, 32);
        int j = j0 + jl;
        if (j < NBANK) {
            if (lg == 0) bank_sq[j] = sq;
            #pragma unroll
            for (int mi = 0; mi < 4; ++mi)
                #pragma unroll
                for (int r = 0; r < 4; ++r) {
                    int m = mi * 16 + lg * 4 + r;
                    key[(size_t)m * NBANK + j] = sq - 2.f * acc[mi][r];
                }
        }
    }
}

// ================= L3: topA (13.3 KB LDS) + 8 LDS-free M2 MFMA blocks =================
__global__ void __launch_bounds__(256) topA_kernel(const float* __restrict__ key,
                                                   float* __restrict__ cand_v,
                                                   int* __restrict__ cand_j,
                                                   const short* __restrict__ invGbf,
                                                   const short* __restrict__ MbfT,
                                                   short* __restrict__ M2T) {
    __shared__ float vals[CHUNKP];
    __shared__ float wv[4];
    __shared__ int wj[4];
    int b = blockIdx.x;
    int t = threadIdx.x;
    if (b < 2048) {
        int n = b >> 5;
        int c = b & 31;
        int base = c * CHUNK;
        const float* row = key + (size_t)n * NBANK + base;
        float lv = __builtin_inff();
        int lj = 0x7fffffff;
        #pragma unroll 13
        for (int i = 0; i < 13; ++i) {
            int j = t + i * 256;
            float v = (j < CHUNK) ? row[j] : __builtin_inff();
            vals[j] = v;
            if (v < lv) { lv = v; lj = j; }
        }
        __syncthreads();
        float* cv = cand_v + (size_t)b * TOPK;
        int* cj = cand_j + (size_t)b * TOPK;
        for (int it = 0; it < TOPK; ++it) {
            float bv = lv; int bj = lj;
            #pragma unroll
            for (int o = 32; o > 0; o >>= 1) {
                float ov = __shfl_down(bv, o);
                int oj = __shfl_down(bj, o);
                if (ov < bv || (ov == bv && oj < bj)) { bv = ov; bj = oj; }
            }
            if ((t & 63) == 0) { wv[t >> 6] = bv; wj[t >> 6] = bj; }
            __syncthreads();
            float gv = wv[0]; int gj = wj[0];
            #pragma unroll
            for (int w2 = 1; w2 < 4; ++w2)
                if (wv[w2] < gv || (wv[w2] == gv && wj[w2] < gj)) { gv = wv[w2]; gj = wj[w2]; }
            if (t == 0) { cv[it] = gv; cj[it] = base + gj; }
            if (t == (gj & 255)) {
                vals[gj] = __builtin_inff();
                lv = __builtin_inff(); lj = 0x7fffffff;
                #pragma unroll 13
                for (int i = 0; i < 13; ++i) {
                    int j = t + i * 256;
                    float v = vals[j];
                    if (v < lv) { lv = v; lj = j; }
                }
            }
            __syncthreads();
        }
    } else {
        // M2T[c][n] = bf16( sum_j invG[n][j] * M[j][c] ), direct-global frags, no LDS
        int c0 = (b - 2048) * 128;
        int wid = t >> 6, l = t & 63, lr = l & 15, lg = l >> 4;
        f32x4 acc[4][2] = {};
        #pragma unroll
        for (int ks = 0; ks < 2; ++ks) {
            bf16x8 af[4], bfr[2];
            #pragma unroll
            for (int mi = 0; mi < 4; ++mi)
                af[mi] = *(const bf16x8*)(invGbf + (mi * 16 + lr) * NCON + ks * 32 + lg * 8);
            #pragma unroll
            for (int ni = 0; ni < 2; ++ni)
                bfr[ni] = *(const bf16x8*)(MbfT + (size_t)(c0 + wid * 32 + ni * 16 + lr) * NCON + ks * 32 + lg * 8);
            #pragma unroll
            for (int mi = 0; mi < 4; ++mi)
                #pragma unroll
                for (int ni = 0; ni < 2; ++ni)
                    acc[mi][ni] = __builtin_amdgcn_mfma_f32_16x16x32_bf16(af[mi], bfr[ni], acc[mi][ni], 0, 0, 0);
        }
        #pragma unroll
        for (int mi = 0; mi < 4; ++mi)
            #pragma unroll
            for (int ni = 0; ni < 2; ++ni)
                #pragma unroll
                for (int r = 0; r < 4; ++r) {
                    int n = mi * 16 + lg * 4 + r;
                    int c = c0 + wid * 32 + ni * 16 + lr;
                    M2T[(size_t)c * NCON + n] = f2bf(acc[mi][ni][r]);
                }
    }
}

// ================= L4: pred = orig GEMM + ypred MFMA + topB =================
__global__ void __launch_bounds__(256) pred_kernel(const short* __restrict__ Xbf,
                                                   const short* __restrict__ WhT,
                                                   const short* __restrict__ XCbf,
                                                   const short* __restrict__ M2T,
                                                   const float* __restrict__ bh,
                                                   const float* __restrict__ cand_v,
                                                   const int* __restrict__ cand_j,
                                                   const float* __restrict__ bank_sq,
                                                   float* __restrict__ orig,
                                                   float* __restrict__ ypred,
                                                   float* __restrict__ dots) {
    __shared__ __align__(16) char smem[32768];
    int b = blockIdx.x;
    int t = threadIdx.x;
    int wid = t >> 6, l = t & 63, lr = l & 15, lg = l >> 4;
    if (b < 512) {
        // ---- orig = Xbf @ WhT^T + bh  [8192 x 1000], K=1024 ----
        short* As = (short*)smem;            // [128][64] bf16
        short* Bs = (short*)(smem + 16384);
        int c0 = (b & 7) * 128;
        int r0 = (b >> 3) * 128;
        int wr = wid >> 1, wc = wid & 1;
        int srow_off = l >> 3;
        int scol = ((l & 7) ^ (l >> 3)) * 8;
        f32x4 acc[4][4] = {};
        for (int kk = 0; kk < DIM; kk += 64) {
            if (kk) __syncthreads();
            #pragma unroll
            for (int i = 0; i < 4; ++i) {
                int si = wid * 4 + i;
                int row = si * 8 + srow_off;
                gload16(Xbf + (size_t)(r0 + row) * DIM + kk + scol, As + si * 512);
                gload16(WhT + (size_t)(c0 + row) * DIM + kk + scol, Bs + si * 512);
            }
            __syncthreads();
            #pragma unroll
            for (int ks = 0; ks < 2; ++ks) {
                bf16x8 af[4], bfr[4];
                #pragma unroll
                for (int mi = 0; mi < 4; ++mi) {
                    int rr = wr * 64 + mi * 16 + lr;
                    int slot = (ks * 4 + lg) ^ (rr & 7);
                    af[mi] = *(const bf16x8*)(As + rr * 64 + slot * 8);
                }
                #pragma unroll
                for (int ni = 0; ni < 4; ++ni) {
                    int cc = wc * 64 + ni * 16 + lr;
                    int slot = (ks * 4 + lg) ^ (cc & 7);
                    bfr[ni] = *(const bf16x8*)(Bs + cc * 64 + slot * 8);
                }
                #pragma unroll
                for (int mi = 0; mi < 4; ++mi)
                    #pragma unroll
                    for (int ni = 0; ni < 4; ++ni)
                        acc[mi][ni] = __builtin_amdgcn_mfma_f32_16x16x32_bf16(af[mi], bfr[ni], acc[mi][ni], 0, 0, 0);
            }
        }
        #pragma unroll
        for (int mi = 0; mi < 4; ++mi)
            #pragma unroll
            for (int ni = 0; ni < 4; ++ni) {
                int col = c0 + wc * 64 + ni * 16 + lr;
                if (col < NCLS) {
                    float bias = bh[col];
                    #pragma unroll
                    for (int r = 0; r < 4; ++r) {
                        int row = r0 + wr * 64 + mi * 16 + lg * 4 + r;
                        orig[(size_t)row * NCLS + col] = acc[mi][ni][r] + bias;
                    }
                }
            }
    } else if (b < 1024) {
        // ---- ypred = XCbf @ M2T^T + bh  [8192 x 1000], K=64, direct-global frags ----
        int q = b - 512;
        int c0 = (q & 7) * 128;
        int r0 = (q >> 3) * 128;
        int wr = wid >> 1, wc = wid & 1;
        f32x4 acc[4][4] = {};
        #pragma unroll
        for (int ks = 0; ks < 2; ++ks) {
            bf16x8 af[4], bfr[4];
            #pragma unroll
            for (int mi = 0; mi < 4; ++mi)
                af[mi] = *(const bf16x8*)(XCbf + (size_t)(r0 + wr * 64 + mi * 16 + lr) * NCON + ks * 32 + lg * 8);
            #pragma unroll
            for (int ni = 0; ni < 4; ++ni)
                bfr[ni] = *(const bf16x8*)(M2T + (size_t)(c0 + wc * 64 + ni * 16 + lr) * NCON + ks * 32 + lg * 8);
            #pragma unroll
            for (int mi = 0; mi < 4; ++mi)
                #pragma unroll
                for (int ni = 0; ni < 4; ++ni)
                    acc[mi][ni] = __builtin_amdgcn_mfma_f32_16x16x32_bf16(af[mi], bfr[ni], acc[mi][ni], 0, 0, 0);
        }
        #pragma unroll
        for (int mi = 0; mi < 4; ++mi)
            #pragma unroll
            for (int ni = 0; ni < 4; ++ni) {
                int col = c0 + wc * 64 + ni * 16 + lr;
                if (col < NCLS) {
                    float bias = bh[col];
                    #pragma unroll
                    for (int r = 0; r < 4; ++r) {
                        int row = r0 + wr * 64 + mi * 16 + lg * 4 + r;
                        ypred[(size_t)row * NCLS + col] = acc[mi][ni][r] + bias;
                    }
                }
            }
    } else {
        // ---- topB: merge 32*50 candidates per concept ----
        int n = b - 1024;
        const int NC2 = NCHUNK * TOPK;  // 1600
        float* vals = (float*)smem;
        int* gidx = (int*)(smem + 6400);
        float* wv = (float*)(smem + 12800);
        int* wj = (int*)(smem + 12816);
        int* wl = (int*)(smem + 12832);
        for (int j = t; j < NC2; j += 256) {
            vals[j] = cand_v[(size_t)n * NC2 + j];
            gidx[j] = cand_j[(size_t)n * NC2 + j];
        }
        __syncthreads();
        float sum = 0.f;
        for (int it = 0; it < TOPK; ++it) {
            float bv = __builtin_inff();
            int bj = 0x7fffffff;
            int bl = -1;
            #pragma unroll 7
            for (int j = t; j < NC2; j += 256) {
                float v = vals[j];
                int gj = gidx[j];
                if (v < bv || (v == bv && gj < bj)) { bv = v; bj = gj; bl = j; }
            }
            #pragma unroll
            for (int o = 32; o > 0; o >>= 1) {
                float ov = __shfl_down(bv, o);
                int oj = __shfl_down(bj, o);
                int ol = __shfl_down(bl, o);
                if (ov < bv || (ov == bv && oj < bj)) { bv = ov; bj = oj; bl = ol; }
            }
            if ((t & 63) == 0) { wv[t >> 6] = bv; wj[t >> 6] = bj; wl[t >> 6] = bl; }
            __syncthreads();
            if (t == 0) {
                #pragma unroll
                for (int w2 = 1; w2 < 4; ++w2)
                    if (wv[w2] < bv || (wv[w2] == bv && wj[w2] < bj)) { bv = wv[w2]; bj = wj[w2]; bl = wl[w2]; }
                sum += 0.5f * (bank_sq[bj] - bv);
                vals[bl] = __builtin_inff();
            }
            __syncthreads();
        }
        if (t == 0) dots[n] = sum / (float)TOPK;
    }
}

// ================= L5: fin (1 block) =================
__global__ void __launch_bounds__(256) fin_kernel(const float* __restrict__ G,
                                                  const float* __restrict__ dots,
                                                  float* __restrict__ out3) {
    __shared__ float r1[256], r2[256], r3[256];
    int t = threadIdx.x;
    float sd = 0.f, so = 0.f;
    for (int u = t; u < 4096; u += 256) {
        float g = G[u];
        if ((u >> 6) == (u & 63)) sd += g; else so += g;
    }
    float s1 = (t < NCON) ? dots[t] : 0.f;
    r1[t] = sd; r2[t] = so; r3[t] = s1;
    __syncthreads();
    for (int o = 128; o > 0; o >>= 1) {
        if (t < o) { r1[t] += r1[t + o]; r2[t] += r2[t + o]; r3[t] += r3[t + o]; }
        __syncthreads();
    }
    if (t == 0) {
        out3[0] = r3[0] / 64.f;
        out3[1] = r2[0] / 4096.f;
        out3[2] = r1[0] / 4096.f;
    }
}

extern "C" void kernel_launch(void* const* d_in, const int* in_sizes, int n_in,
                              void* d_out, int out_size, void* d_ws, size_t ws_size,
                              hipStream_t stream) {
    const float* X    = (const float*)d_in[0];
    const float* cpt  = (const float*)d_in[1];
    const float* bank = (const float*)d_in[2];
    const float* Wh   = (const float*)d_in[3];
    const float* bh   = (const float*)d_in[4];
    float* out = (float*)d_out;

    float* orig  = out;
    float* ypred = out + Y_OFF;
    float* out3  = out + S_OFF;

    char* w = (char*)d_ws;
    short* Xbf    = (short*)(w);               // 16,777,216 B
    short* WhT    = (short*)(w + 16777216);    //  2,097,152 B  [1024][1024] bf16
    short* cptT   = (short*)(w + 18874368);    //    131,072 B
    short* XCbf   = (short*)(w + 19005440);    //  1,048,576 B  [8192][64] bf16
    short* M2T    = (short*)(w + 20054016);    //    131,072 B  [1024][64] bf16
    float* key    = (float*)(w + 20185088);    // 25,600,000 B
    float* bank_sq= (float*)(w + 45785088);    //    400,384 B
    float* G      = (float*)(w + 46185472);    //     16,384 B
    short* invGbf = (short*)(w + 46201856);    //      8,192 B  [64][64] bf16
    short* MbfT   = (short*)(w + 46210048);    //    131,072 B  [1024][64] bf16
    float* cand_v = (float*)(w + 46341120);    //    409,600 B
    int*   cand_j = (int*)  (w + 46750720);    //    409,600 B
    float* dots   = (float*)(w + 47160320);    //        256 B

    prep_kernel<<<272, 256, 0, stream>>>(cpt, Wh, WhT, cptT);
    mid_kernel<<<73 + NDIST, 256, 0, stream>>>(bank, X, cptT, WhT, Xbf, XCbf, key, bank_sq, MbfT, G, invGbf);
    topA_kernel<<<2056, 256, 0, stream>>>(key, cand_v, cand_j, invGbf, MbfT, M2T);
    pred_kernel<<<1088, 256, 0, stream>>>(Xbf, WhT, XCbf, M2T, bh, cand_v, cand_j, bank_sq, orig, ypred, dots);
    fin_kernel<<<1, 256, 0, stream>>>(G, dots, out3);
}

// Round 19
// 375.745 us; speedup vs baseline: 1.0995x; 1.0063x over previous
//
#include <hip/hip_runtime.h>
#include <cstddef>

#define BSZ   8192
#define DIM   1024
#define NCON  64
#define NBANK 100000
#define NCLS  1000
#define TOPK  50
#define NCHUNK 32
#define CHUNK  3125    // 32 * 3125 = 100000
#define CHUNKP 3328    // 13 * 256 (padded with +inf)
#define NDIST 1563     // 1563 * 64 = 100032 >= 100000

#define Y_OFF 8192000
#define S_OFF 16384000

typedef __attribute__((ext_vector_type(8))) short bf16x8;
typedef __attribute__((ext_vector_type(4))) float f32x4;

__device__ __forceinline__ short f2bf(float x) {
    unsigned u = __builtin_bit_cast(unsigned, x);
    unsigned r = (u + 0x7fffu + ((u >> 16) & 1u)) >> 16;
    return (short)r;
}

__device__ __forceinline__ bf16x8 pack8(f32x4 a, f32x4 b) {
    bf16x8 p;
    p[0] = f2bf(a[0]); p[1] = f2bf(a[1]); p[2] = f2bf(a[2]); p[3] = f2bf(a[3]);
    p[4] = f2bf(b[0]); p[5] = f2bf(b[1]); p[6] = f2bf(b[2]); p[7] = f2bf(b[3]);
    return p;
}

// lds base must be WAVE-UNIFORM; hardware writes base + lane*16.
__device__ __forceinline__ void gload16(const void* g, void* l) {
    __builtin_amdgcn_global_load_lds(
        (__attribute__((address_space(1))) void*)g,
        (__attribute__((address_space(3))) void*)l,
        16, 0, 0);
}

// ================= L1: prep =================
// 0..255: Wh^T -> WhT [1024][1024] bf16 (cols>=1000 zero) ; 256..271: cpt -> cptT
__global__ void __launch_bounds__(256) prep_kernel(const float* __restrict__ cpt,
                                                   const float* __restrict__ Wh,
                                                   short* __restrict__ WhT,
                                                   short* __restrict__ cptT) {
    __shared__ short Ts[64][65];
    int b = blockIdx.x;
    int t = threadIdx.x;
    if (b < 256) {
        int k0 = (b & 15) * 64, n0 = (b >> 4) * 64;
        #pragma unroll
        for (int i = 0; i < 16; ++i) {
            int u = i * 256 + t;
            int kL = u >> 6, nL = u & 63;
            int n = n0 + nL;
            Ts[kL][nL] = (n < NCLS) ? f2bf(Wh[(size_t)(k0 + kL) * NCLS + n]) : (short)0;
        }
        __syncthreads();
        #pragma unroll
        for (int i = 0; i < 16; ++i) {
            int u = i * 256 + t;
            int nL = u >> 6, kL = u & 63;
            WhT[(size_t)(n0 + nL) * DIM + k0 + kL] = Ts[kL][nL];
        }
    } else {
        int q = b - 256;
        #pragma unroll
        for (int i = 0; i < 16; ++i) {
            int u = q * 4096 + i * 256 + t;
            int d = u >> 6, n = u & 63;
            cptT[n * DIM + d] = f2bf(cpt[u]);
        }
    }
}

// ================= L2: mid =================
// 0..7: MbfT ; 8: G+invGbf ; 9..72: XC (+ Xbf) ; 73..1635: dist (BK=64, counted vmcnt)
__global__ void __launch_bounds__(256) mid_kernel(const float* __restrict__ bank,
                                                  const float* __restrict__ X,
                                                  const short* __restrict__ cptT,
                                                  const short* __restrict__ WhT,
                                                  short* __restrict__ Xbf,
                                                  short* __restrict__ XCbf,
                                                  float* __restrict__ key,
                                                  float* __restrict__ bank_sq,
                                                  short* __restrict__ MbfT,
                                                  float* __restrict__ G,
                                                  short* __restrict__ invGbf) {
    __shared__ __align__(16) char smem[49152];  // dist: 2x16KB bank + 2x8KB cpt ; GJ: 512B
    int b = blockIdx.x;
    int t = threadIdx.x;
    int wid = t >> 6, l = t & 63, lr = l & 15, lg = l >> 4;
    if (b < 8) {
        // ---- MbfT[c][m] = bf16( (C^T @ Wh)[m][c] ) ----
        int c0 = b * 128;
        f32x4 acc[4][2] = {};
        for (int kk = 0; kk < DIM; kk += 32) {
            bf16x8 af[4], bfr[2];
            #pragma unroll
            for (int mi = 0; mi < 4; ++mi)
                af[mi] = *(const bf16x8*)(cptT + (mi * 16 + lr) * DIM + kk + lg * 8);
            #pragma unroll
            for (int ni = 0; ni < 2; ++ni)
                bfr[ni] = *(const bf16x8*)(WhT + (size_t)(c0 + wid * 32 + ni * 16 + lr) * DIM + kk + lg * 8);
            #pragma unroll
            for (int mi = 0; mi < 4; ++mi)
                #pragma unroll
                for (int ni = 0; ni < 2; ++ni)
                    acc[mi][ni] = __builtin_amdgcn_mfma_f32_16x16x32_bf16(af[mi], bfr[ni], acc[mi][ni], 0, 0, 0);
        }
        #pragma unroll
        for (int mi = 0; mi < 4; ++mi)
            #pragma unroll
            for (int ni = 0; ni < 2; ++ni)
                #pragma unroll
                for (int r = 0; r < 4; ++r) {
                    int m = mi * 16 + lg * 4 + r;
                    int c = c0 + wid * 32 + ni * 16 + lr;
                    MbfT[(size_t)c * NCON + m] = f2bf(acc[mi][ni][r]);
                }
    } else if (b == 8) {
        // ---- G = C^T C via MFMA, then register Gauss-Jordan -> invGbf ----
        float* rowk = (float*)smem;
        float* fk = (float*)(smem + 256);
        f32x4 acc[4] = {};
        for (int kk = 0; kk < DIM; kk += 32) {
            bf16x8 af[4], bfr;
            #pragma unroll
            for (int mi = 0; mi < 4; ++mi)
                af[mi] = *(const bf16x8*)(cptT + (mi * 16 + lr) * DIM + kk + lg * 8);
            bfr = *(const bf16x8*)(cptT + (wid * 16 + lr) * DIM + kk + lg * 8);
            #pragma unroll
            for (int mi = 0; mi < 4; ++mi)
                acc[mi] = __builtin_amdgcn_mfma_f32_16x16x32_bf16(af[mi], bfr, acc[mi], 0, 0, 0);
        }
        #pragma unroll
        for (int mi = 0; mi < 4; ++mi)
            #pragma unroll
            for (int r = 0; r < 4; ++r)
                G[(mi * 16 + lg * 4 + r) * 64 + wid * 16 + lr] = acc[mi][r];
        __syncthreads();   // drain vmcnt: G visible to own reads via L2
        float myA[16];
        #pragma unroll
        for (int s = 0; s < 16; ++s) myA[s] = G[(4 * s + wid) * 64 + l];
        #pragma unroll
        for (int k = 0; k < 64; ++k) {
            if (wid == (k & 3)) rowk[l] = myA[k >> 2];
            if (l == k) {
                #pragma unroll
                for (int s = 0; s < 16; ++s) fk[4 * s + wid] = myA[s];
            }
            __syncthreads();
            float ip = 1.f / rowk[k];
            float rv = rowk[l];
            #pragma unroll
            for (int s = 0; s < 16; ++s) {
                int i = 4 * s + wid;
                float fv = fk[i];
                float nv;
                if (i == k && l == k)      nv = ip;
                else if (i == k)           nv = rv * ip;
                else if (l == k)           nv = -fv * ip;
                else                       nv = myA[s] - fv * (rv * ip);
                myA[s] = nv;
            }
            __syncthreads();
        }
        #pragma unroll
        for (int s = 0; s < 16; ++s) invGbf[(4 * s + wid) * 64 + l] = f2bf(myA[s]);
    } else if (b < 73) {
        // ---- XC = X @ C (also writes Xbf bf16) ----
        int r0 = (b - 9) * 128;
        int r_[2];
        const float* xrow[2];
        #pragma unroll
        for (int ni = 0; ni < 2; ++ni) {
            r_[ni] = r0 + wid * 32 + ni * 16 + lr;
            xrow[ni] = X + (size_t)r_[ni] * DIM + lg * 8;
        }
        f32x4 acc[4][2] = {};
        for (int kk = 0; kk < DIM; kk += 32) {
            bf16x8 af[4];
            #pragma unroll
            for (int mi = 0; mi < 4; ++mi)
                af[mi] = *(const bf16x8*)(cptT + (mi * 16 + lr) * DIM + kk + lg * 8);
            #pragma unroll
            for (int ni = 0; ni < 2; ++ni) {
                f32x4 a = *(const f32x4*)(xrow[ni] + kk);
                f32x4 c = *(const f32x4*)(xrow[ni] + kk + 4);
                bf16x8 pk = pack8(a, c);
                *(bf16x8*)(Xbf + (size_t)r_[ni] * DIM + kk + lg * 8) = pk;
                #pragma unroll
                for (int mi = 0; mi < 4; ++mi)
                    acc[mi][ni] = __builtin_amdgcn_mfma_f32_16x16x32_bf16(af[mi], pk, acc[mi][ni], 0, 0, 0);
            }
        }
        #pragma unroll
        for (int mi = 0; mi < 4; ++mi)
            #pragma unroll
            for (int ni = 0; ni < 2; ++ni)
                #pragma unroll
                for (int r = 0; r < 4; ++r) {
                    int m = mi * 16 + lg * 4 + r;
                    XCbf[(size_t)r_[ni] * NCON + m] = f2bf(acc[mi][ni][r]);
                }
    } else {
        // ---- dist: 64 j/block, BK=64, dbuf staging with COUNTED vmcnt (T4) ----
        // Per K-step: issue next tile's 6 gload_lds, wait vmcnt(6) (current tile's
        // 6 oldest land), raw barrier, compute; trailing barrier protects the buffer
        // about to be overwritten. Next-tile loads stay in flight across compute.
        int j0 = (b - 73) * 64;
        int bj4[4], bs4[4];
        #pragma unroll
        for (int i = 0; i < 4; ++i) {
            int flat = i * 4096 + wid * 1024 + l * 16;   // byte in 16KB tile
            bj4[i] = flat >> 8;                           // row j (256 B/row)
            bs4[i] = ((flat >> 4) & 15) ^ (bj4[i] & 15);  // global segment for this slot
        }
        int cm2[2], cs2[2];
        #pragma unroll
        for (int i = 0; i < 2; ++i) {
            int flat = i * 4096 + wid * 1024 + l * 16;   // byte in 8KB tile
            cm2[i] = flat >> 7;                           // row m (128 B/row)
            cs2[i] = ((flat >> 4) & 7) ^ (cm2[i] & 7);
        }
        int jl = wid * 16 + lr;
        f32x4 acc[4] = {};
        float sq = 0.f;
        // prologue: stage step 0 into buffer 0 (6 vmem ops per wave)
        #pragma unroll
        for (int i = 0; i < 4; ++i) {
            int jr = j0 + bj4[i]; if (jr >= NBANK) jr = NBANK - 1;
            gload16(bank + (size_t)jr * DIM + bs4[i] * 4, smem + i * 4096 + wid * 1024);
        }
        #pragma unroll
        for (int i = 0; i < 2; ++i)
            gload16(cptT + cm2[i] * DIM + cs2[i] * 8, smem + 32768 + i * 4096 + wid * 1024);
        int buf = 0;
        for (int kk = 0; kk < DIM; kk += 64) {
            int kn = kk + 64;
            int nb = buf ^ 1;
            bool more = kn < DIM;
            if (more) {
                #pragma unroll
                for (int i = 0; i < 4; ++i) {
                    int jr = j0 + bj4[i]; if (jr >= NBANK) jr = NBANK - 1;
                    gload16(bank + (size_t)jr * DIM + kn + bs4[i] * 4,
                            smem + nb * 16384 + i * 4096 + wid * 1024);
                }
                #pragma unroll
                for (int i = 0; i < 2; ++i)
                    gload16(cptT + cm2[i] * DIM + kn + cs2[i] * 8,
                            smem + 32768 + nb * 8192 + i * 4096 + wid * 1024);
                asm volatile("s_waitcnt vmcnt(6)" ::: "memory");
            } else {
                asm volatile("s_waitcnt vmcnt(0)" ::: "memory");
            }
            __builtin_amdgcn_s_barrier();          // current tile visible to all waves
            __builtin_amdgcn_sched_barrier(0);     // pin ds_reads below the barrier
            const float* bT = (const float*)(smem + buf * 16384);
            const short* cS = (const short*)(smem + 32768 + buf * 8192);
            #pragma unroll
            for (int ks = 0; ks < 2; ++ks) {
                bf16x8 af[4];
                #pragma unroll
                for (int mi = 0; mi < 4; ++mi) {
                    int m = mi * 16 + lr;
                    af[mi] = *(const bf16x8*)(cS + m * 64 + (((ks * 4 + lg) ^ (m & 7)) << 3));
                }
                int g0 = ks * 8 + lg * 2;
                f32x4 a = *(const f32x4*)(bT + jl * 64 + ((g0 ^ (jl & 15)) << 2));
                f32x4 c = *(const f32x4*)(bT + jl * 64 + (((g0 + 1) ^ (jl & 15)) << 2));
                sq += a[0]*a[0] + a[1]*a[1] + a[2]*a[2] + a[3]*a[3]
                    + c[0]*c[0] + c[1]*c[1] + c[2]*c[2] + c[3]*c[3];
                bf16x8 pk = pack8(a, c);
                #pragma unroll
                for (int mi = 0; mi < 4; ++mi)
                    acc[mi] = __builtin_amdgcn_mfma_f32_16x16x32_bf16(af[mi], pk, acc[mi], 0, 0, 0);
            }
            __builtin_amdgcn_sched_barrier(0);     // pin ds_reads above the drain
            asm volatile("s_waitcnt lgkmcnt(0)" ::: "memory");
            __builtin_amdgcn_s_barrier();          // reads done before buf is overwritten
            buf ^= 1;
        }
        sq += __shfl_xor(sq, 16);
        sq += __shfl_xor(sq, 32);
        int j = j0 + jl;
        if (j < NBANK) {
            if (lg == 0) bank_sq[j] = sq;
            #pragma unroll
            for (int mi = 0; mi < 4; ++mi)
                #pragma unroll
                for (int r = 0; r < 4; ++r) {
                    int m = mi * 16 + lg * 4 + r;
                    key[(size_t)m * NBANK + j] = sq - 2.f * acc[mi][r];
                }
        }
    }
}

// ================= L3: topA (13.3 KB LDS) + 8 LDS-free M2 MFMA blocks =================
__global__ void __launch_bounds__(256) topA_kernel(const float* __restrict__ key,
                                                   float* __restrict__ cand_v,
                                                   int* __restrict__ cand_j,
                                                   const short* __restrict__ invGbf,
                                                   const short* __restrict__ MbfT,
                                                   short* __restrict__ M2T) {
    __shared__ float vals[CHUNKP];
    __shared__ float wv[4];
    __shared__ int wj[4];
    int b = blockIdx.x;
    int t = threadIdx.x;
    if (b < 2048) {
        int n = b >> 5;
        int c = b & 31;
        int base = c * CHUNK;
        const float* row = key + (size_t)n * NBANK + base;
        float lv = __builtin_inff();
        int lj = 0x7fffffff;
        #pragma unroll 13
        for (int i = 0; i < 13; ++i) {
            int j = t + i * 256;
            float v = (j < CHUNK) ? row[j] : __builtin_inff();
            vals[j] = v;
            if (v < lv) { lv = v; lj = j; }
        }
        __syncthreads();
        float* cv = cand_v + (size_t)b * TOPK;
        int* cj = cand_j + (size_t)b * TOPK;
        for (int it = 0; it < TOPK; ++it) {
            float bv = lv; int bj = lj;
            #pragma unroll
            for (int o = 32; o > 0; o >>= 1) {
                float ov = __shfl_down(bv, o);
                int oj = __shfl_down(bj, o);
                if (ov < bv || (ov == bv && oj < bj)) { bv = ov; bj = oj; }
            }
            if ((t & 63) == 0) { wv[t >> 6] = bv; wj[t >> 6] = bj; }
            __syncthreads();
            float gv = wv[0]; int gj = wj[0];
            #pragma unroll
            for (int w2 = 1; w2 < 4; ++w2)
                if (wv[w2] < gv || (wv[w2] == gv && wj[w2] < gj)) { gv = wv[w2]; gj = wj[w2]; }
            if (t == 0) { cv[it] = gv; cj[it] = base + gj; }
            if (t == (gj & 255)) {
                vals[gj] = __builtin_inff();
                lv = __builtin_inff(); lj = 0x7fffffff;
                #pragma unroll 13
                for (int i = 0; i < 13; ++i) {
                    int j = t + i * 256;
                    float v = vals[j];
                    if (v < lv) { lv = v; lj = j; }
                }
            }
            __syncthreads();
        }
    } else {
        // M2T[c][n] = bf16( sum_j invG[n][j] * M[j][c] ), direct-global frags, no LDS
        int c0 = (b - 2048) * 128;
        int wid = t >> 6, l = t & 63, lr = l & 15, lg = l >> 4;
        f32x4 acc[4][2] = {};
        #pragma unroll
        for (int ks = 0; ks < 2; ++ks) {
            bf16x8 af[4], bfr[2];
            #pragma unroll
            for (int mi = 0; mi < 4; ++mi)
                af[mi] = *(const bf16x8*)(invGbf + (mi * 16 + lr) * NCON + ks * 32 + lg * 8);
            #pragma unroll
            for (int ni = 0; ni < 2; ++ni)
                bfr[ni] = *(const bf16x8*)(MbfT + (size_t)(c0 + wid * 32 + ni * 16 + lr) * NCON + ks * 32 + lg * 8);
            #pragma unroll
            for (int mi = 0; mi < 4; ++mi)
                #pragma unroll
                for (int ni = 0; ni < 2; ++ni)
                    acc[mi][ni] = __builtin_amdgcn_mfma_f32_16x16x32_bf16(af[mi], bfr[ni], acc[mi][ni], 0, 0, 0);
        }
        #pragma unroll
        for (int mi = 0; mi < 4; ++mi)
            #pragma unroll
            for (int ni = 0; ni < 2; ++ni)
                #pragma unroll
                for (int r = 0; r < 4; ++r) {
                    int n = mi * 16 + lg * 4 + r;
                    int c = c0 + wid * 32 + ni * 16 + lr;
                    M2T[(size_t)c * NCON + n] = f2bf(acc[mi][ni][r]);
                }
    }
}

// ================= L4: pred = orig GEMM + ypred MFMA + topB =================
__global__ void __launch_bounds__(256) pred_kernel(const short* __restrict__ Xbf,
                                                   const short* __restrict__ WhT,
                                                   const short* __restrict__ XCbf,
                                                   const short* __restrict__ M2T,
                                                   const float* __restrict__ bh,
                                                   const float* __restrict__ cand_v,
                                                   const int* __restrict__ cand_j,
                                                   const float* __restrict__ bank_sq,
                                                   float* __restrict__ orig,
                                                   float* __restrict__ ypred,
                                                   float* __restrict__ dots) {
    __shared__ __align__(16) char smem[32768];
    int b = blockIdx.x;
    int t = threadIdx.x;
    int wid = t >> 6, l = t & 63, lr = l & 15, lg = l >> 4;
    if (b < 512) {
        // ---- orig = Xbf @ WhT^T + bh  [8192 x 1000], K=1024 ----
        short* As = (short*)smem;            // [128][64] bf16
        short* Bs = (short*)(smem + 16384);
        int c0 = (b & 7) * 128;
        int r0 = (b >> 3) * 128;
        int wr = wid >> 1, wc = wid & 1;
        int srow_off = l >> 3;
        int scol = ((l & 7) ^ (l >> 3)) * 8;
        f32x4 acc[4][4] = {};
        for (int kk = 0; kk < DIM; kk += 64) {
            if (kk) __syncthreads();
            #pragma unroll
            for (int i = 0; i < 4; ++i) {
                int si = wid * 4 + i;
                int row = si * 8 + srow_off;
                gload16(Xbf + (size_t)(r0 + row) * DIM + kk + scol, As + si * 512);
                gload16(WhT + (size_t)(c0 + row) * DIM + kk + scol, Bs + si * 512);
            }
            __syncthreads();
            #pragma unroll
            for (int ks = 0; ks < 2; ++ks) {
                bf16x8 af[4], bfr[4];
                #pragma unroll
                for (int mi = 0; mi < 4; ++mi) {
                    int rr = wr * 64 + mi * 16 + lr;
                    int slot = (ks * 4 + lg) ^ (rr & 7);
                    af[mi] = *(const bf16x8*)(As + rr * 64 + slot * 8);
                }
                #pragma unroll
                for (int ni = 0; ni < 4; ++ni) {
                    int cc = wc * 64 + ni * 16 + lr;
                    int slot = (ks * 4 + lg) ^ (cc & 7);
                    bfr[ni] = *(const bf16x8*)(Bs + cc * 64 + slot * 8);
                }
                #pragma unroll
                for (int mi = 0; mi < 4; ++mi)
                    #pragma unroll
                    for (int ni = 0; ni < 4; ++ni)
                        acc[mi][ni] = __builtin_amdgcn_mfma_f32_16x16x32_bf16(af[mi], bfr[ni], acc[mi][ni], 0, 0, 0);
            }
        }
        #pragma unroll
        for (int mi = 0; mi < 4; ++mi)
            #pragma unroll
            for (int ni = 0; ni < 4; ++ni) {
                int col = c0 + wc * 64 + ni * 16 + lr;
                if (col < NCLS) {
                    float bias = bh[col];
                    #pragma unroll
                    for (int r = 0; r < 4; ++r) {
                        int row = r0 + wr * 64 + mi * 16 + lg * 4 + r;
                        orig[(size_t)row * NCLS + col] = acc[mi][ni][r] + bias;
                    }
                }
            }
    } else if (b < 1024) {
        // ---- ypred = XCbf @ M2T^T + bh  [8192 x 1000], K=64, direct-global frags ----
        int q = b - 512;
        int c0 = (q & 7) * 128;
        int r0 = (q >> 3) * 128;
        int wr = wid >> 1, wc = wid & 1;
        f32x4 acc[4][4] = {};
        #pragma unroll
        for (int ks = 0; ks < 2; ++ks) {
            bf16x8 af[4], bfr[4];
            #pragma unroll
            for (int mi = 0; mi < 4; ++mi)
                af[mi] = *(const bf16x8*)(XCbf + (size_t)(r0 + wr * 64 + mi * 16 + lr) * NCON + ks * 32 + lg * 8);
            #pragma unroll
            for (int ni = 0; ni < 4; ++ni)
                bfr[ni] = *(const bf16x8*)(M2T + (size_t)(c0 + wc * 64 + ni * 16 + lr) * NCON + ks * 32 + lg * 8);
            #pragma unroll
            for (int mi = 0; mi < 4; ++mi)
                #pragma unroll
                for (int ni = 0; ni < 4; ++ni)
                    acc[mi][ni] = __builtin_amdgcn_mfma_f32_16x16x32_bf16(af[mi], bfr[ni], acc[mi][ni], 0, 0, 0);
        }
        #pragma unroll
        for (int mi = 0; mi < 4; ++mi)
            #pragma unroll
            for (int ni = 0; ni < 4; ++ni) {
                int col = c0 + wc * 64 + ni * 16 + lr;
                if (col < NCLS) {
                    float bias = bh[col];
                    #pragma unroll
                    for (int r = 0; r < 4; ++r) {
                        int row = r0 + wr * 64 + mi * 16 + lg * 4 + r;
                        ypred[(size_t)row * NCLS + col] = acc[mi][ni][r] + bias;
                    }
                }
            }
    } else {
        // ---- topB: merge 32*50 candidates per concept ----
        int n = b - 1024;
        const int NC2 = NCHUNK * TOPK;  // 1600
        float* vals = (float*)smem;
        int* gidx = (int*)(smem + 6400);
        float* wv = (float*)(smem + 12800);
        int* wj = (int*)(smem + 12816);
        int* wl = (int*)(smem + 12832);
        for (int j = t; j < NC2; j += 256) {
            vals[j] = cand_v[(size_t)n * NC2 + j];
            gidx[j] = cand_j[(size_t)n * NC2 + j];
        }
        __syncthreads();
        float sum = 0.f;
        for (int it = 0; it < TOPK; ++it) {
            float bv = __builtin_inff();
            int bj = 0x7fffffff;
            int bl = -1;
            #pragma unroll 7
            for (int j = t; j < NC2; j += 256) {
                float v = vals[j];
                int gj = gidx[j];
                if (v < bv || (v == bv && gj < bj)) { bv = v; bj = gj; bl = j; }
            }
            #pragma unroll
            for (int o = 32; o > 0; o >>= 1) {
                float ov = __shfl_down(bv, o);
                int oj = __shfl_down(bj, o);
                int ol = __shfl_down(bl, o);
                if (ov < bv || (ov == bv && oj < bj)) { bv = ov; bj = oj; bl = ol; }
            }
            if ((t & 63) == 0) { wv[t >> 6] = bv; wj[t >> 6] = bj; wl[t >> 6] = bl; }
            __syncthreads();
            if (t == 0) {
                #pragma unroll
                for (int w2 = 1; w2 < 4; ++w2)
                    if (wv[w2] < bv || (wv[w2] == bv && wj[w2] < bj)) { bv = wv[w2]; bj = wj[w2]; bl = wl[w2]; }
                sum += 0.5f * (bank_sq[bj] - bv);
                vals[bl] = __builtin_inff();
            }
            __syncthreads();
        }
        if (t == 0) dots[n] = sum / (float)TOPK;
    }
}

// ================= L5: fin (1 block) =================
__global__ void __launch_bounds__(256) fin_kernel(const float* __restrict__ G,
                                                  const float* __restrict__ dots,
                                                  float* __restrict__ out3) {
    __shared__ float r1[256], r2[256], r3[256];
    int t = threadIdx.x;
    float sd = 0.f, so = 0.f;
    for (int u = t; u < 4096; u += 256) {
        float g = G[u];
        if ((u >> 6) == (u & 63)) sd += g; else so += g;
    }
    float s1 = (t < NCON) ? dots[t] : 0.f;
    r1[t] = sd; r2[t] = so; r3[t] = s1;
    __syncthreads();
    for (int o = 128; o > 0; o >>= 1) {
        if (t < o) { r1[t] += r1[t + o]; r2[t] += r2[t + o]; r3[t] += r3[t + o]; }
        __syncthreads();
    }
    if (t == 0) {
        out3[0] = r3[0] / 64.f;
        out3[1] = r2[0] / 4096.f;
        out3[2] = r1[0] / 4096.f;
    }
}

extern "C" void kernel_launch(void* const* d_in, const int* in_sizes, int n_in,
                              void* d_out, int out_size, void* d_ws, size_t ws_size,
                              hipStream_t stream) {
    const float* X    = (const float*)d_in[0];
    const float* cpt  = (const float*)d_in[1];
    const float* bank = (const float*)d_in[2];
    const float* Wh   = (const float*)d_in[3];
    const float* bh   = (const float*)d_in[4];
    float* out = (float*)d_out;

    float* orig  = out;
    float* ypred = out + Y_OFF;
    float* out3  = out + S_OFF;

    char* w = (char*)d_ws;
    short* Xbf    = (short*)(w);               // 16,777,216 B
    short* WhT    = (short*)(w + 16777216);    //  2,097,152 B  [1024][1024] bf16
    short* cptT   = (short*)(w + 18874368);    //    131,072 B
    short* XCbf   = (short*)(w + 19005440);    //  1,048,576 B  [8192][64] bf16
    short* M2T    = (short*)(w + 20054016);    //    131,072 B  [1024][64] bf16
    float* key    = (float*)(w + 20185088);    // 25,600,000 B
    float* bank_sq= (float*)(w + 45785088);    //    400,384 B
    float* G      = (float*)(w + 46185472);    //     16,384 B
    short* invGbf = (short*)(w + 46201856);    //      8,192 B  [64][64] bf16
    short* MbfT   = (short*)(w + 46210048);    //    131,072 B  [1024][64] bf16
    float* cand_v = (float*)(w + 46341120);    //    409,600 B
    int*   cand_j = (int*)  (w + 46750720);    //    409,600 B
    float* dots   = (float*)(w + 47160320);    //        256 B

    prep_kernel<<<272, 256, 0, stream>>>(cpt, Wh, WhT, cptT);
    mid_kernel<<<73 + NDIST, 256, 0, stream>>>(bank, X, cptT, WhT, Xbf, XCbf, key, bank_sq, MbfT, G, invGbf);
    topA_kernel<<<2056, 256, 0, stream>>>(key, cand_v, cand_j, invGbf, MbfT, M2T);
    pred_kernel<<<1088, 256, 0, stream>>>(Xbf, WhT, XCbf, M2T, bh, cand_v, cand_j, bank_sq, orig, ypred, dots);
    fin_kernel<<<1, 256, 0, stream>>>(G, dots, out3);
}